// Round 1
// baseline (218.009 us; speedup 1.0000x reference)
//
#include <hip/hip_runtime.h>
#include <hip/hip_bf16.h>

// Problem geometry (compile-time constants from the reference)
#define GATE 512
#define MB   256          // meta-batch (M)
#define NTOT 120581       // total concatenated param count (N)
#define BN   64           // output columns per workgroup

typedef __attribute__((ext_vector_type(8))) short short8;   // 8 bf16 (4 VGPRs)
typedef __attribute__((ext_vector_type(4))) float  f32x4;

struct GemmParams {
    const float* W[10];
    const float* p[10];
    const float* bias[10];
};

__device__ __forceinline__ short bf16bits(float x) {
    __hip_bfloat16 h = __float2bfloat16(x);   // RTNE
    return *reinterpret_cast<short*>(&h);
}

__global__ void emb_to_bf16(const float* __restrict__ emb,
                            unsigned short* __restrict__ o, int n) {
    int i = blockIdx.x * blockDim.x + threadIdx.x;
    if (i < n) {
        __hip_bfloat16 h = __float2bfloat16(emb[i]);
        o[i] = *reinterpret_cast<unsigned short*>(&h);
    }
}

// One workgroup: 256 rows x 64 cols of output. 4 waves, wave w does rows [64w,64w+64).
// A = emb (bf16, precomputed in ws), B^T = W rows (fp32 in global, cvt in-register).
__global__ __launch_bounds__(256) void gate_gemm(GemmParams P,
                                                 const unsigned short* __restrict__ embw,
                                                 float* __restrict__ out)
{
    constexpr int kStarts[11] = {0, 1728, 1792, 38656, 38720, 75584,
                                 75648, 112512, 112576, 120576, 120581};

    const int lane = threadIdx.x & 63;
    const int wave = threadIdx.x >> 6;
    const int col0 = blockIdx.x * BN;
    const int lr = lane & 15;   // frag row (A) / frag col (B, C)
    const int lg = lane >> 4;   // k-group / C row-group

    // Per-lane column metadata for the 4 N-fragments
    const float* wrow[4];
    float pv[4], bv[4];
    bool  valid[4];
#pragma unroll
    for (int nf = 0; nf < 4; ++nf) {
        int n  = col0 + nf * 16 + lr;
        int nc = n < NTOT ? n : NTOT - 1;
        int t  = 0;
#pragma unroll
        for (int i = 1; i < 10; ++i) t += (nc >= kStarts[i]);
        int r = nc - kStarts[t];
        wrow[nf]  = P.W[t] + (size_t)r * GATE;
        pv[nf]    = P.p[t][r];
        bv[nf]    = P.bias[t][r];
        valid[nf] = (n < NTOT);
    }

    // A row pointers (bf16 emb), 4 M-fragments for this wave
    const unsigned short* arow[4];
#pragma unroll
    for (int mf = 0; mf < 4; ++mf)
        arow[mf] = embw + (size_t)(wave * 64 + mf * 16 + lr) * GATE;

    f32x4 acc[4][4];
#pragma unroll
    for (int i = 0; i < 4; ++i)
#pragma unroll
        for (int j = 0; j < 4; ++j)
            acc[i][j] = (f32x4){0.f, 0.f, 0.f, 0.f};

    for (int kb = 0; kb < GATE; kb += 32) {
        const int k0 = kb + lg * 8;

        short8 afrag[4];
#pragma unroll
        for (int mf = 0; mf < 4; ++mf)
            afrag[mf] = *(const short8*)(arow[mf] + k0);

        short8 bfrag[4];
#pragma unroll
        for (int nf = 0; nf < 4; ++nf) {
            f32x4 w0 = *(const f32x4*)(wrow[nf] + k0);
            f32x4 w1 = *(const f32x4*)(wrow[nf] + k0 + 4);
            short8 bb;
#pragma unroll
            for (int j = 0; j < 4; ++j) bb[j] = bf16bits(w0[j]);
#pragma unroll
            for (int j = 0; j < 4; ++j) bb[4 + j] = bf16bits(w1[j]);
            bfrag[nf] = bb;
        }

#pragma unroll
        for (int mf = 0; mf < 4; ++mf)
#pragma unroll
            for (int nf = 0; nf < 4; ++nf)
                acc[mf][nf] = __builtin_amdgcn_mfma_f32_16x16x32_bf16(
                    afrag[mf], bfrag[nf], acc[mf][nf], 0, 0, 0);
    }

    // Epilogue: sigmoid(x + b) * p, store fp32.
    // Verified C/D mapping: col = lane&15, row = (lane>>4)*4 + reg.
#pragma unroll
    for (int nf = 0; nf < 4; ++nf) {
        if (!valid[nf]) continue;
        const int n = col0 + nf * 16 + lr;
#pragma unroll
        for (int mf = 0; mf < 4; ++mf) {
#pragma unroll
            for (int r = 0; r < 4; ++r) {
                int m = wave * 64 + mf * 16 + lg * 4 + r;
                float x = acc[mf][nf][r] + bv[nf];
                float e = __expf(-x);
                float eta = __builtin_amdgcn_rcpf(1.0f + e);
                out[(size_t)m * NTOT + n] = eta * pv[nf];
            }
        }
    }
}

extern "C" void kernel_launch(void* const* d_in, const int* in_sizes, int n_in,
                              void* d_out, int out_size, void* d_ws, size_t ws_size,
                              hipStream_t stream) {
    const float* emb = (const float*)d_in[0];
    GemmParams P;
    for (int i = 0; i < 10; ++i) {
        P.p[i]    = (const float*)d_in[1 + 3 * i];
        P.W[i]    = (const float*)d_in[2 + 3 * i];
        P.bias[i] = (const float*)d_in[3 + 3 * i];
    }

    unsigned short* embw = (unsigned short*)d_ws;   // 256*512*2 = 256 KB
    emb_to_bf16<<<(MB * GATE + 255) / 256, 256, 0, stream>>>(emb, embw, MB * GATE);

    int nblocks = (NTOT + BN - 1) / BN;   // 1885
    gate_gemm<<<nblocks, 256, 0, stream>>>(P, embw, (float*)d_out);
}

// Round 2
// 131.329 us; speedup vs baseline: 1.6600x; 1.6600x over previous
//
#include <hip/hip_runtime.h>
#include <hip/hip_bf16.h>

#define GATE 512
#define MROWS 256
#define NTOT 120581

typedef __attribute__((ext_vector_type(8))) short short8;   // 8 bf16
typedef __attribute__((ext_vector_type(4))) float  f32x4;

struct GemmParams {
    const float* W[10];
    const float* p[10];
    const float* bias[10];
};

__device__ __forceinline__ short bf16bits(float x) {
    __hip_bfloat16 h = __float2bfloat16(x);   // RTNE
    return *reinterpret_cast<short*>(&h);
}

// emb fp32 -> bf16, 8 elems/thread, vectorized
__global__ void emb_to_bf16(const float* __restrict__ emb,
                            unsigned short* __restrict__ o) {
    int i = (blockIdx.x * blockDim.x + threadIdx.x) * 8;
    f32x4 a = *(const f32x4*)(emb + i);
    f32x4 b = *(const f32x4*)(emb + i + 4);
    short8 r;
#pragma unroll
    for (int j = 0; j < 4; ++j) { r[j] = bf16bits(a[j]); r[4 + j] = bf16bits(b[j]); }
    *(short8*)(o + i) = r;
}

// Block: 256 rows x 64 cols. Wave w owns cols [w*16, w*16+16), ALL 256 rows.
// A staged in LDS (double-buffered, K-step 32, swizzled); B (W rows) register-prefetched.
__global__ __launch_bounds__(256, 4) void gate_gemm(GemmParams P,
                                                    const unsigned short* __restrict__ embw,
                                                    float* __restrict__ out)
{
    constexpr int kStarts[11] = {0, 1728, 1792, 38656, 38720, 75584,
                                 75648, 112512, 112576, 120576, 120581};
    __shared__ unsigned short Atile[2][MROWS * 32];   // 2 x 16 KB

    const int t    = threadIdx.x;
    const int lane = t & 63;
    const int wave = t >> 6;
    const int lr   = lane & 15;   // frag col (B/C) / frag row (A)
    const int lg   = lane >> 4;   // k-group / C row-group

    // This lane's single output column
    const int  n     = blockIdx.x * 64 + wave * 16 + lr;
    const bool valid = n < NTOT;
    const int  nc    = valid ? n : NTOT - 1;
    int tt = 0;
#pragma unroll
    for (int i = 1; i < 10; ++i) tt += (nc >= kStarts[i]);
    const int rr = nc - kStarts[tt];
    const float* wrow = P.W[tt] + (size_t)rr * GATE + lg * 8;
    const float pv = P.p[tt][rr];
    const float bv = P.bias[tt][rr];

    // A staging: pre-swizzled global source (LDS dest stays linear).
    // LDS linear 16B-unit l = i*256 + t -> (row = l>>2, slot = l&3);
    // content must be embw[row][kb + (slot ^ ((row>>1)&3))*8 .. +8].
    const int srow  = t >> 2;
    const int sslot = (t & 3) ^ ((t >> 3) & 3);
    const unsigned short* asrc = embw + (size_t)srow * GATE + sslot * 8;

    // A read: row = mf*16 + lr, slot = lg ^ ((lr>>1)&3)
    const int aslot = lg ^ ((lr >> 1) & 3);
    const int abase = lr * 32 + aslot * 8;   // ushort index; + mf*512

    f32x4 acc[16];
#pragma unroll
    for (int i = 0; i < 16; ++i) acc[i] = (f32x4){0.f, 0.f, 0.f, 0.f};

    auto stage = [&](int buf, int kb) {
#pragma unroll
        for (int i = 0; i < 4; ++i) {
            const unsigned short* src = asrc + (size_t)i * 64 * GATE + kb;
            unsigned short* dst = &Atile[buf][(size_t)(i * 256 + t) * 8];
            __builtin_amdgcn_global_load_lds(
                (const __attribute__((address_space(1))) void*)src,
                (__attribute__((address_space(3))) void*)dst, 16, 0, 0);
        }
    };

    // Prologue: stage K-step 0, prefetch B for K-step 0
    stage(0, 0);
    f32x4 b0 = *(const f32x4*)(wrow);
    f32x4 b1 = *(const f32x4*)(wrow + 4);
    __syncthreads();   // drains vmcnt -> Atile[0] ready, b0/b1 ready

    int buf = 0;
#pragma unroll
    for (int ks = 0; ks < 16; ++ks) {
        f32x4 nb0, nb1;
        if (ks < 15) {
            stage(buf ^ 1, (ks + 1) * 32);               // async A prefetch
            nb0 = *(const f32x4*)(wrow + (ks + 1) * 32); // B reg prefetch
            nb1 = *(const f32x4*)(wrow + (ks + 1) * 32 + 4);
        }

        short8 bfrag;
#pragma unroll
        for (int j = 0; j < 4; ++j) {
            bfrag[j]     = bf16bits(b0[j]);
            bfrag[4 + j] = bf16bits(b1[j]);
        }

        const unsigned short* ab = &Atile[buf][abase];
#pragma unroll
        for (int mf = 0; mf < 16; ++mf) {
            short8 afrag = *(const short8*)(ab + mf * 512);
            acc[mf] = __builtin_amdgcn_mfma_f32_16x16x32_bf16(afrag, bfrag, acc[mf], 0, 0, 0);
        }

        __syncthreads();   // reads of buf done + stage(buf^1) drained
        b0 = nb0; b1 = nb1;
        buf ^= 1;
    }

    // Epilogue: sigmoid(x + b) * p. C/D map: col = lane&15, row = (lane>>4)*4 + reg.
    if (valid) {
        float* ocol = out + n;
#pragma unroll
        for (int mf = 0; mf < 16; ++mf) {
            const int m0 = mf * 16 + lg * 4;
#pragma unroll
            for (int q = 0; q < 4; ++q) {
                float x   = acc[mf][q] + bv;
                float e   = __expf(-x);
                float eta = __builtin_amdgcn_rcpf(1.0f + e);
                ocol[(size_t)(m0 + q) * NTOT] = eta * pv;
            }
        }
    }
}

extern "C" void kernel_launch(void* const* d_in, const int* in_sizes, int n_in,
                              void* d_out, int out_size, void* d_ws, size_t ws_size,
                              hipStream_t stream) {
    const float* emb = (const float*)d_in[0];
    GemmParams P;
    for (int i = 0; i < 10; ++i) {
        P.p[i]    = (const float*)d_in[1 + 3 * i];
        P.W[i]    = (const float*)d_in[2 + 3 * i];
        P.bias[i] = (const float*)d_in[3 + 3 * i];
    }

    unsigned short* embw = (unsigned short*)d_ws;   // 256 KB
    emb_to_bf16<<<(MROWS * GATE) / (256 * 8), 256, 0, stream>>>(emb, embw);

    int nblocks = (NTOT + 63) / 64;   // 1885
    gate_gemm<<<nblocks, 256, 0, stream>>>(P, embw, (float*)d_out);
}